// Round 7
// baseline (650.525 us; speedup 1.0000x reference)
//
#include <hip/hip_runtime.h>
#include <hip/hip_bf16.h>
#include <cstddef>

#define B_ 4
#define S_ 2048
#define D_ 2048
#define H_ 16
#define DH_ 128
#define QKS_ 4096

typedef __attribute__((ext_vector_type(8))) short bfrag8;
typedef __attribute__((ext_vector_type(4))) float ffrag4;
typedef __attribute__((ext_vector_type(4))) int ifrag4;

typedef const __attribute__((address_space(1))) void* gptr1;
typedef __attribute__((address_space(3))) void* lptr3;
#define GL16(g, l) __builtin_amdgcn_global_load_lds((gptr1)(g), (lptr3)(l), 16, 0, 0)
#define LDSU(p) ((unsigned)(unsigned long long)(lptr3)(p))

#define BARRIER() { asm volatile("" ::: "memory"); __builtin_amdgcn_s_barrier(); asm volatile("" ::: "memory"); }
#define VMW8() asm volatile("s_waitcnt vmcnt(8)" ::: "memory")
#define VMW6() asm volatile("s_waitcnt vmcnt(6)" ::: "memory")
#define VMW4() asm volatile("s_waitcnt vmcnt(4)" ::: "memory")
#define VMW0() asm volatile("s_waitcnt vmcnt(0)" ::: "memory")
// Counted lgkm wait + scheduler fence (rule 18): MFMA after this waits only for reads
// OLDER than the N newest outstanding DS ops.
#define LGKM(n) { asm volatile("s_waitcnt lgkmcnt(" #n ")" ::: "memory"); __builtin_amdgcn_sched_barrier(0); }

// inline-asm ds_read_b128 from a 32-bit LDS byte address; stays outstanding until a
// counted lgkmcnt drains it (the compiler would otherwise emit a conservative wait
// that serializes the LDS pipe against the MFMA pipe -- round-5 measured exactly
// the serial sum: 5218 cyc/K-tile = 2483 MFMA + ~2800 LDS).
__device__ __forceinline__ bfrag8 DSR128(unsigned a) {
  ifrag4 r;
  asm volatile("ds_read_b128 %0, %1" : "=v"(r) : "v"(a));
  return __builtin_bit_cast(bfrag8, r);
}

__device__ __forceinline__ short f2bf(float f) {
  unsigned u = __float_as_uint(f);
  u = (u + 0x7FFFu + ((u >> 16) & 1u)) >> 16;
  return (short)u;
}
__device__ __forceinline__ float bf2f(short s) {
  return __uint_as_float(((unsigned)(unsigned short)s) << 16);
}
__device__ __forceinline__ unsigned pk2(float lo, float hi) {
  unsigned a = __float_as_uint(lo);
  a = (a + 0x7FFFu + ((a >> 16) & 1u)) >> 16;
  unsigned b = __float_as_uint(hi);
  b = (b + 0x7FFFu + ((b >> 16) & 1u)) & 0xFFFF0000u;
  return a | b;
}

// ---------------- RoPE cos/sin table: tab[s*32+p] = {cos,sin}(s * 10000^(-2p/64)) ----------------
__global__ __launch_bounds__(256) void rope_tab_kernel(float2* __restrict__ tab) {
  int idx = blockIdx.x * 256 + threadIdx.x;   // 65536
  int s = idx >> 5, p = idx & 31;
  float invf = exp2f(-(float)p * (13.287712379549449f / 32.0f));
  float sn, cs;
  sincosf((float)s * invf, &sn, &cs);
  tab[idx] = make_float2(cs, sn);
}

// ---------------- LayerNorm: fp32 X -> bf16 Xn ----------------
__global__ __launch_bounds__(256) void ln_kernel(const float* __restrict__ X,
    const float* __restrict__ w, const float* __restrict__ bta,
    short* __restrict__ Xn) {
  int row = blockIdx.x;
  int tid = threadIdx.x;
  const float* xr = X + (size_t)row * D_;
  float x[8];
  float4 v0 = *(const float4*)(xr + tid * 4);
  float4 v1 = *(const float4*)(xr + 1024 + tid * 4);
  x[0] = v0.x; x[1] = v0.y; x[2] = v0.z; x[3] = v0.w;
  x[4] = v1.x; x[5] = v1.y; x[6] = v1.z; x[7] = v1.w;
  float sum = 0.f, ssq = 0.f;
#pragma unroll
  for (int i = 0; i < 8; i++) { sum += x[i]; ssq += x[i] * x[i]; }
#pragma unroll
  for (int off = 1; off < 64; off <<= 1) {
    sum += __shfl_xor(sum, off, 64);
    ssq += __shfl_xor(ssq, off, 64);
  }
  __shared__ float s1[4], s2[4];
  int wave = tid >> 6;
  if ((tid & 63) == 0) { s1[wave] = sum; s2[wave] = ssq; }
  __syncthreads();
  sum = s1[0] + s1[1] + s1[2] + s1[3];
  ssq = s2[0] + s2[1] + s2[2] + s2[3];
  float mu = sum * (1.0f / D_);
  float var = ssq * (1.0f / D_) - mu * mu;
  float rs = rsqrtf(var + 1e-5f);
  short* orow = Xn + (size_t)row * D_;
#pragma unroll
  for (int i = 0; i < 8; i++) {
    int col = (i < 4) ? (tid * 4 + i) : (1024 + tid * 4 + (i - 4));
    float xn = (x[i] - mu) * rs * w[col] + bta[col];
    orow[col] = f2bf(xn);
  }
}

// ---------------- Transpose + cast: W (RxC fp32) -> WT (CxR bf16) ----------------
__global__ __launch_bounds__(256) void transpose_cvt(const float* __restrict__ W,
    short* __restrict__ WT, int R, int C) {
  __shared__ float t[32][33];
  int tx = threadIdx.x, ty = threadIdx.y;
  int c0 = blockIdx.x * 32, r0 = blockIdx.y * 32;
#pragma unroll
  for (int i = 0; i < 4; i++)
    t[ty + i * 8][tx] = W[(size_t)(r0 + ty + i * 8) * C + c0 + tx];
  __syncthreads();
#pragma unroll
  for (int i = 0; i < 4; i++)
    WT[(size_t)(c0 + ty + i * 8) * R + r0 + tx] = f2bf(t[tx][ty + i * 8]);
}

// ---------------- GEMM: 256x256 block, 8 waves (2Mx4N), BK=64 ----------------
// ROUND-7 == ROUND-6 resubmit (container infra flake; kernel audited hang-free:
// uniform barrier counts, waitcnts always drain).
// Register-double-buffered 4-cluster pipeline + MANUAL counted lgkmcnt.
// Each cluster: BARRIER -> asm ds_read next frags -> STG -> LGKM(n) -> MFMA.
// LGKM counts (DS completes in order per wave): C1:4 (drains C4's 8), C2:8 (drains
// C1's 4), C3:4 (drains C2's 8), C4: S1?8:0 (drains C3's 4). Each cluster's fresh
// reads stay outstanding THROUGH its MFMA -> LDS pipe overlaps matrix pipe.
//   C1: rd A-hi0->afB      | STG A-k1(t+1) | LGKM(4) MFMA(afA,bfA,acc0-3) | VMW6
//   C2: rd B1->bfB,lo1->afA| STG B-k1(t+1) | LGKM(8) MFMA(afB,bfA,acc4-7)
//   C3: rd A-hi1->afB      | STG A-k0(t+2) | LGKM(4) MFMA(afA,bfB,acc0-3) | VMW6
//   C4: rd B0',lo0' (S1)   | STG B-k0(t+2) | LGKM(8/0) MFMA(afB,bfB,acc4-7)
// vmcnt rule: VMW before a BARRIER, dependent ds_reads after it. WAR: every STG into
// a region is >=1 barrier after the last reads of it were lgkm-drained.
// LDS geometry: [dbuf][khalf][256][32] bf16; half = h<<14 B, dbuf slot = d<<15 B.
// Swizzle: chunk c of row r at c^((r>>1)&3) (conflict-free, round-2 verified 0).
// XCD swizzle (T1, bijective) as round 4 (FETCH 182->150 MB).
template<int EPI>
__global__ __launch_bounds__(512, 2) void gemm_bt(const short* __restrict__ A,
    const short* __restrict__ Bt, short* __restrict__ Cb, short* __restrict__ Vt,
    const float2* __restrict__ tab, float* __restrict__ Cf,
    const float* __restrict__ resid, int M, int N, int K) {
  __shared__ __align__(16) short lA[2][2][256][32];
  __shared__ __align__(16) short lB[2][2][256][32];
  int tid = threadIdx.x;
  int wave = tid >> 6, lane = tid & 63;
  int m16 = lane & 15, quad = lane >> 4;
  int wm = (wave >> 2) * 128, wn = (wave & 3) * 64;

  // T1 chunked XCD swizzle
  int bid = blockIdx.x;
  int q = bid & 7, c = bid >> 3;
  int xb = c >> 2;
  int yb = (q << 2) | (c & 3);
  int m0 = yb * 256, n0 = xb * 256;

  const ffrag4 fzero = {0.f, 0.f, 0.f, 0.f};
  ffrag4 acc[8][4];
#pragma unroll
  for (int i = 0; i < 8; i++)
#pragma unroll
    for (int j = 0; j < 4; j++) acc[i][j] = fzero;

  // ---- hoisted staging addresses (swizzle folded into the global source) ----
  int r0_ = tid >> 2;                                   // rows 0..127
  int csw = ((tid & 3) ^ ((r0_ >> 1) & 3)) << 3;        // swizzled 8-short chunk
  const short* gA0 = A + (size_t)(m0 + r0_) * K + csw;
  const short* gA1 = A + (size_t)(m0 + r0_ + 128) * K + csw;
  const short* gB0 = Bt + (size_t)(n0 + r0_) * K + csw;
  const short* gB1 = Bt + (size_t)(n0 + r0_ + 128) * K + csw;
  int ldW = wave << 10;                                 // byte offset of this wave's slab

  // stage half h of K-tile kt into buffer d: 2 GL16/thread, linear LDS dest
#define STG(g0, g1, larr, kt, h, d) { \
    const short* s0_ = (g0) + ((size_t)(kt) << 6) + ((h) << 5); \
    const short* s1_ = (g1) + ((size_t)(kt) << 6) + ((h) << 5); \
    char* dst_ = (char*)(larr) + (((d) << 15) | ((h) << 14)) + ldW; \
    GL16(s0_, dst_); \
    GL16(s1_, dst_ + 8192); }

  // ---- hoisted ds_read byte offsets within one [256][32] half ----
  unsigned offA[8], offB[4];
#pragma unroll
  for (int mi = 0; mi < 8; mi++) {
    int ra = wm + mi * 16 + m16;
    offA[mi] = (unsigned)(ra * 64 + ((quad ^ ((ra >> 1) & 3)) << 4));
  }
#pragma unroll
  for (int ni = 0; ni < 4; ni++) {
    int rb = wn + ni * 16 + m16;
    offB[ni] = (unsigned)(rb * 64 + ((quad ^ ((rb >> 1) & 3)) << 4));
  }
  unsigned aLds = LDSU(&lA[0][0][0][0]);
  unsigned bLds = LDSU(&lB[0][0][0][0]);

  bfrag8 afA[4], afB[4], bfA[4], bfB[4];

#define MF16(AF, BF, BASE) { \
    __builtin_amdgcn_s_setprio(1); \
    _Pragma("unroll") \
    for (int mi_ = 0; mi_ < 4; mi_++) \
      _Pragma("unroll") \
      for (int ni_ = 0; ni_ < 4; ni_++) \
        acc[(BASE) + mi_][ni_] = __builtin_amdgcn_mfma_f32_16x16x32_bf16( \
            AF[mi_], BF[ni_], acc[(BASE) + mi_][ni_], 0, 0, 0); \
    __builtin_amdgcn_s_setprio(0); }

#define KTILE(T, S1, S2) { \
    const int cur_ = (T) & 1, nxt_ = cur_ ^ 1; \
    const unsigned h0_ = (unsigned)(cur_ << 15); \
    const unsigned h1_ = h0_ | 16384u; \
    const unsigned g0_ = (unsigned)(nxt_ << 15); \
    /* C1 */ \
    BARRIER(); \
    afB[0] = DSR128(aLds + h0_ + offA[4]); \
    afB[1] = DSR128(aLds + h0_ + offA[5]); \
    afB[2] = DSR128(aLds + h0_ + offA[6]); \
    afB[3] = DSR128(aLds + h0_ + offA[7]); \
    if (S1) STG(gA0, gA1, lA, (T) + 1, 1, nxt_); \
    LGKM(4); \
    MF16(afA, bfA, 0); \
    if (S1) { VMW6(); } else { VMW0(); } \
    /* C2 */ \
    BARRIER(); \
    bfB[0] = DSR128(bLds + h1_ + offB[0]); \
    bfB[1] = DSR128(bLds + h1_ + offB[1]); \
    bfB[2] = DSR128(bLds + h1_ + offB[2]); \
    bfB[3] = DSR128(bLds + h1_ + offB[3]); \
    afA[0] = DSR128(aLds + h1_ + offA[0]); \
    afA[1] = DSR128(aLds + h1_ + offA[1]); \
    afA[2] = DSR128(aLds + h1_ + offA[2]); \
    afA[3] = DSR128(aLds + h1_ + offA[3]); \
    if (S1) STG(gB0, gB1, lB, (T) + 1, 1, nxt_); \
    LGKM(8); \
    MF16(afB, bfA, 4); \
    /* C3 */ \
    BARRIER(); \
    afB[0] = DSR128(aLds + h1_ + offA[4]); \
    afB[1] = DSR128(aLds + h1_ + offA[5]); \
    afB[2] = DSR128(aLds + h1_ + offA[6]); \
    afB[3] = DSR128(aLds + h1_ + offA[7]); \
    if (S2) STG(gA0, gA1, lA, (T) + 2, 0, cur_); \
    LGKM(4); \
    MF16(afA, bfB, 0); \
    if (S2) { VMW6(); } else if (S1) { VMW4(); } \
    /* C4 */ \
    BARRIER(); \
    if (S1) { \
      bfA[0] = DSR128(bLds + g0_ + offB[0]); \
      bfA[1] = DSR128(bLds + g0_ + offB[1]); \
      bfA[2] = DSR128(bLds + g0_ + offB[2]); \
      bfA[3] = DSR128(bLds + g0_ + offB[3]); \
      afA[0] = DSR128(aLds + g0_ + offA[0]); \
      afA[1] = DSR128(aLds + g0_ + offA[1]); \
      afA[2] = DSR128(aLds + g0_ + offA[2]); \
      afA[3] = DSR128(aLds + g0_ + offA[3]); \
    } \
    if (S2) STG(gB0, gB1, lB, (T) + 2, 0, cur_); \
    if (S1) { LGKM(8); } else { LGKM(0); } \
    MF16(afB, bfB, 4); \
  }

  // prologue: k0(0)->[0][0], k1(0)->[0][1], k0(1)->[1][0]; VMW8 forces k0(0); then
  // pre-read C1(0)'s fragments (B0 + A-lo0) after the barrier.
  STG(gA0, gA1, lA, 0, 0, 0); STG(gB0, gB1, lB, 0, 0, 0);
  STG(gA0, gA1, lA, 0, 1, 0); STG(gB0, gB1, lB, 0, 1, 0);
  STG(gA0, gA1, lA, 1, 0, 1); STG(gB0, gB1, lB, 1, 0, 1);
  VMW8();
  BARRIER();
  bfA[0] = DSR128(bLds + offB[0]);
  bfA[1] = DSR128(bLds + offB[1]);
  bfA[2] = DSR128(bLds + offB[2]);
  bfA[3] = DSR128(bLds + offB[3]);
  afA[0] = DSR128(aLds + offA[0]);
  afA[1] = DSR128(aLds + offA[1]);
  afA[2] = DSR128(aLds + offA[2]);
  afA[3] = DSR128(aLds + offA[3]);

  int nK = K >> 6;
  for (int t = 0; t < nK - 2; ++t) KTILE(t, 1, 1);
  KTILE(nK - 2, 1, 0);
  KTILE(nK - 1, 0, 0);
#undef KTILE
#undef MF16
#undef STG

  // ---- epilogue ----
#pragma unroll
  for (int mi = 0; mi < 8; mi++) {
    int rowb = m0 + wm + mi * 16 + quad * 4;
#pragma unroll
    for (int ni = 0; ni < 4; ni++) {
      int col = n0 + wn + ni * 16 + m16;
      if (EPI == 1) {
#pragma unroll
        for (int r = 0; r < 4; r++) {
          size_t idx = (size_t)(rowb + r) * N + col;
          Cf[idx] = acc[mi][ni][r] + resid[idx];
        }
      } else if (n0 >= 4096) {
        // V: direct store in Vt (b,h,Dh,S) layout, 4 consecutive s as short4
        int d = col - 4096;
        short4 pk;
        pk.x = f2bf(acc[mi][ni][0]);
        pk.y = f2bf(acc[mi][ni][1]);
        pk.z = f2bf(acc[mi][ni][2]);
        pk.w = f2bf(acc[mi][ni][3]);
        *(short4*)(Vt + ((size_t)((rowb >> 11) * H_ + (d >> 7)) * DH_ + (d & 127)) * S_ +
                   (rowb & (S_ - 1))) = pk;
      } else if ((col & 127) < 64) {
        // fused RoPE on Q/K via table
        int p = (col & 127) >> 1;
        float sgn = (col & 1) ? 1.0f : -1.0f;
#pragma unroll
        for (int r = 0; r < 4; r++) {
          float own = acc[mi][ni][r];
          float prt = __shfl_xor(own, 1, 64);
          float2 cssn = tab[((rowb + r) & (S_ - 1)) * 32 + p];
          Cb[(size_t)(rowb + r) * QKS_ + col] = f2bf(own * cssn.x + sgn * prt * cssn.y);
        }
      } else {
#pragma unroll
        for (int r = 0; r < 4; r++)
          Cb[(size_t)(rowb + r) * QKS_ + col] = f2bf(acc[mi][ni][r]);
      }
    }
  }
}

// ---------------- Flash attention, S^T form ----------------
__global__ __launch_bounds__(512) void attn_kernel(const short* __restrict__ qkv,
    const short* __restrict__ Vt, short* __restrict__ ctx) {
  __shared__ __align__(16) short lK[2][64 * 128];   // [key][d]  16 KiB each
  __shared__ __align__(16) short lV[2][128 * 64];   // [d][key]  16 KiB each
  int tid = threadIdx.x;
  int wave = tid >> 6, lane = tid & 63;
  int m16 = lane & 15, quad = lane >> 4;
  int bh = blockIdx.y;
  int b = bh >> 4, h = bh & 15;
  int qbase = blockIdx.x * 256 + wave * 32;

  const float qscale = 1.4426950408889634f * 0.08838834764831845f;
  bfrag8 qf[2][4];
#pragma unroll
  for (int qb = 0; qb < 2; qb++)
#pragma unroll
    for (int kc = 0; kc < 4; kc++) {
      bfrag8 q = *(const bfrag8*)(qkv +
          (size_t)(b * S_ + qbase + qb * 16 + m16) * QKS_ + h * DH_ + kc * 32 + quad * 8);
#pragma unroll
      for (int j = 0; j < 8; j++) q[j] = f2bf(bf2f(q[j]) * qscale);
      qf[qb][kc] = q;
    }

  const ffrag4 fzero = {0.f, 0.f, 0.f, 0.f};
  ffrag4 oacc[2][8];
#pragma unroll
  for (int qb = 0; qb < 2; qb++)
#pragma unroll
    for (int nd = 0; nd < 8; nd++) oacc[qb][nd] = fzero;
  float lpart[2] = {0.f, 0.f};

  int krow = lane >> 4;
  int kcb = lane & 15;
  int vrow = lane >> 3;
  int vcb = lane & 7;

  {
#pragma unroll
    for (int i = 0; i < 2; i++) {
      int c = wave + i * 8;
      int r = c * 4 + krow;
      int sb = kcb ^ (r & 15);
      GL16(qkv + (size_t)(b * S_ + r) * QKS_ + D_ + h * DH_ + sb * 8, &lK[0][c * 512]);
    }
#pragma unroll
    for (int i = 0; i < 2; i++) {
      int c = wave + i * 8;
      int r = c * 8 + vrow;
      int sb = vcb ^ (r & 7);
      GL16(Vt + (size_t)(bh * DH_ + r) * S_ + sb * 8, &lV[0][c * 512]);
    }
  }
  __syncthreads();

  for (int kt = 0; kt < 32; kt++) {
    int cur = kt & 1;
    if (kt < 31) {
      int sk0 = (kt + 1) * 64;
      int nb = cur ^ 1;
#pragma unroll
      for (int i = 0; i < 2; i++) {
        int c = wave + i * 8;
        int r = c * 4 + krow;
        int sb = kcb ^ (r & 15);
        GL16(qkv + (size_t)(b * S_ + sk0 + r) * QKS_ + D_ + h * DH_ + sb * 8, &lK[nb][c * 512]);
      }
#pragma unroll
      for (int i = 0; i < 2; i++) {
        int c = wave + i * 8;
        int r = c * 8 + vrow;
        int sb = vcb ^ (r & 7);
        GL16(Vt + (size_t)(bh * DH_ + r) * S_ + sk0 + sb * 8, &lV[nb][c * 512]);
      }
    }

    const short* kb = &lK[cur][0];
    const short* vb = &lV[cur][0];

    ffrag4 sacc[2][4];
#pragma unroll
    for (int qb = 0; qb < 2; qb++)
#pragma unroll
      for (int ntk = 0; ntk < 4; ntk++) sacc[qb][ntk] = fzero;
#pragma unroll
    for (int ntk = 0; ntk < 4; ntk++)
#pragma unroll
      for (int kc = 0; kc < 4; kc++) {
        bfrag8 kf = *(const bfrag8*)(kb + (ntk * 16 + m16) * 128 +
                                     (((kc * 4 + quad) ^ m16) << 3));
        sacc[0][ntk] = __builtin_amdgcn_mfma_f32_16x16x32_bf16(kf, qf[0][kc], sacc[0][ntk], 0, 0, 0);
        sacc[1][ntk] = __builtin_amdgcn_mfma_f32_16x16x32_bf16(kf, qf[1][kc], sacc[1][ntk], 0, 0, 0);
      }

    bfrag8 pA[2][2];
#pragma unroll
    for (int qb = 0; qb < 2; qb++) {
      unsigned Xp[4][2];
      float ls = 0.f;
#pragma unroll
      for (int ntk = 0; ntk < 4; ntk++) {
        float e0 = exp2f(sacc[qb][ntk][0]);
        float e1 = exp2f(sacc[qb][ntk][1]);
        float e2 = exp2f(sacc[qb][ntk][2]);
        float e3 = exp2f(sacc[qb][ntk][3]);
        ls += (e0 + e1) + (e2 + e3);
        Xp[ntk][0] = pk2(e0, e1);
        Xp[ntk][1] = pk2(e2, e3);
      }
      lpart[qb] += ls;
#pragma unroll
      for (int kc = 0; kc < 2; kc++) {
        unsigned x0 = Xp[2 * kc][0], x1 = Xp[2 * kc][1];
        unsigned y0 = Xp[2 * kc + 1][0], y1 = Xp[2 * kc + 1][1];
        asm("v_permlane32_swap_b32 %0, %1" : "+v"(x0), "+v"(y0));
        asm("v_permlane16_swap_b32 %0, %1" : "+v"(x0), "+v"(y0));
        asm("v_permlane32_swap_b32 %0, %1" : "+v"(x1), "+v"(y1));
        asm("v_permlane16_swap_b32 %0, %1" : "+v"(x1), "+v"(y1));
        union { int4 i4; bfrag8 b8; } u;
        u.i4 = (int4){(int)x0, (int)x1, (int)y0, (int)y1};
        pA[qb][kc] = u.b8;
      }
    }

#pragma unroll
    for (int kc = 0; kc < 2; kc++)
#pragma unroll
      for (int nd = 0; nd < 8; nd++) {
        bfrag8 vf = *(const bfrag8*)(vb + (nd * 16 + m16) * 64 +
                                     (((kc * 4 + quad) ^ (m16 & 7)) << 3));
        oacc[0][nd] = __builtin_amdgcn_mfma_f32_16x16x32_bf16(pA[0][kc], vf, oacc[0][nd], 0, 0, 0);
        oacc[1][nd] = __builtin_amdgcn_mfma_f32_16x16x32_bf16(pA[1][kc], vf, oacc[1][nd], 0, 0, 0);
      }

    __syncthreads();
  }

#pragma unroll
  for (int qb = 0; qb < 2; qb++) {
    lpart[qb] += __shfl_xor(lpart[qb], 16, 64);
    lpart[qb] += __shfl_xor(lpart[qb], 32, 64);
  }
#pragma unroll
  for (int qb = 0; qb < 2; qb++) {
    float inv[4];
#pragma unroll
    for (int r = 0; r < 4; r++) inv[r] = 1.0f / __shfl(lpart[qb], quad * 4 + r, 64);
#pragma unroll
    for (int nd = 0; nd < 8; nd++)
#pragma unroll
      for (int r = 0; r < 4; r++) {
        int row = qbase + qb * 16 + quad * 4 + r;
        int col = h * DH_ + nd * 16 + m16;
        ctx[(size_t)(b * S_ + row) * D_ + col] = f2bf(oacc[qb][nd][r] * inv[r]);
      }
  }
}

// ---------------- launch ----------------
extern "C" void kernel_launch(void* const* d_in, const int* in_sizes, int n_in,
                              void* d_out, int out_size, void* d_ws, size_t ws_size,
                              hipStream_t stream) {
  const float* X    = (const float*)d_in[0];
  const float* lnw  = (const float*)d_in[1];
  const float* lnb  = (const float*)d_in[2];
  const float* Win  = (const float*)d_in[3];
  const float* Wout = (const float*)d_in[4];
  float* out = (float*)d_out;
  char* ws = (char*)d_ws;
  short*  Xn    = (short*)(ws + 0);          //  32 MiB: 8192x2048 bf16
  short*  WinT  = (short*)(ws + 33554432);   //  24 MiB: 6144x2048 bf16
  short*  WoutT = (short*)(ws + 58720256);   //   8 MiB: 2048x2048 bf16
  short*  qkv   = (short*)(ws + 67108864);   //  64 MiB: 8192x4096 bf16 (Q,K only)
  short*  Vt    = (short*)(ws + 134217728);  //  32 MiB: (b,h,128,2048) bf16
  short*  ctx   = (short*)(ws + 167772160);  //  32 MiB: 8192x2048 bf16
  float2* tab   = (float2*)(ws + 201326592); // 512 KiB: 2048x32 cos/sin

  rope_tab_kernel<<<256, 256, 0, stream>>>(tab);
  transpose_cvt<<<dim3(192, 64), dim3(32, 8), 0, stream>>>(Win, WinT, 2048, 6144);
  transpose_cvt<<<dim3(64, 64), dim3(32, 8), 0, stream>>>(Wout, WoutT, 2048, 2048);
  ln_kernel<<<8192, 256, 0, stream>>>(X, lnw, lnb, Xn);
  gemm_bt<0><<<768, 512, 0, stream>>>(Xn, WinT, qkv, Vt, tab, nullptr, nullptr, 8192, 6144, 2048);
  attn_kernel<<<dim3(8, 64), 512, 0, stream>>>(qkv, Vt, ctx);
  gemm_bt<1><<<256, 512, 0, stream>>>(ctx, WoutT, nullptr, nullptr, nullptr, out, X, 8192, 2048, 2048);
}

// Round 8
// 635.641 us; speedup vs baseline: 1.0234x; 1.0234x over previous
//
#include <hip/hip_runtime.h>
#include <hip/hip_bf16.h>
#include <cstddef>

#define B_ 4
#define S_ 2048
#define D_ 2048
#define H_ 16
#define DH_ 128
#define QKS_ 4096

typedef __attribute__((ext_vector_type(8))) short bfrag8;
typedef __attribute__((ext_vector_type(4))) float ffrag4;
typedef __attribute__((ext_vector_type(4))) int ifrag4;

typedef const __attribute__((address_space(1))) void* gptr1;
typedef __attribute__((address_space(3))) void* lptr3;
#define GL16(g, l) __builtin_amdgcn_global_load_lds((gptr1)(g), (lptr3)(l), 16, 0, 0)
#define LDSU(p) ((unsigned)(unsigned long long)(lptr3)(p))

#define BARRIER() { asm volatile("" ::: "memory"); __builtin_amdgcn_s_barrier(); asm volatile("" ::: "memory"); }
#define VMW8() asm volatile("s_waitcnt vmcnt(8)" ::: "memory")
#define VMW6() asm volatile("s_waitcnt vmcnt(6)" ::: "memory")
#define VMW4() asm volatile("s_waitcnt vmcnt(4)" ::: "memory")
#define VMW0() asm volatile("s_waitcnt vmcnt(0)" ::: "memory")
// Counted lgkm wait + scheduler fence (rule 18): MFMA after this waits only for reads
// OLDER than the N newest outstanding DS ops.
#define LGKM(n) { asm volatile("s_waitcnt lgkmcnt(" #n ")" ::: "memory"); __builtin_amdgcn_sched_barrier(0); }

// inline-asm ds_read_b128 from a 32-bit LDS byte address; stays outstanding until a
// counted lgkmcnt drains it.
__device__ __forceinline__ bfrag8 DSR128(unsigned a) {
  ifrag4 r;
  asm volatile("ds_read_b128 %0, %1" : "=v"(r) : "v"(a));
  return __builtin_bit_cast(bfrag8, r);
}

__device__ __forceinline__ short f2bf(float f) {
  unsigned u = __float_as_uint(f);
  u = (u + 0x7FFFu + ((u >> 16) & 1u)) >> 16;
  return (short)u;
}
__device__ __forceinline__ float bf2f(short s) {
  return __uint_as_float(((unsigned)(unsigned short)s) << 16);
}
// HW packed f32->bf16x2 (RNE), 1 instr vs ~7 for the manual round (T12 primitive).
__device__ __forceinline__ unsigned cvtpk(float lo, float hi) {
  unsigned r;
  asm("v_cvt_pk_bf16_f32 %0, %1, %2" : "=v"(r) : "v"(lo), "v"(hi));
  return r;
}

// ---------------- RoPE cos/sin table: tab[s*32+p] = {cos,sin}(s * 10000^(-2p/64)) ----------------
__global__ __launch_bounds__(256) void rope_tab_kernel(float2* __restrict__ tab) {
  int idx = blockIdx.x * 256 + threadIdx.x;   // 65536
  int s = idx >> 5, p = idx & 31;
  float invf = exp2f(-(float)p * (13.287712379549449f / 32.0f));
  float sn, cs;
  sincosf((float)s * invf, &sn, &cs);
  tab[idx] = make_float2(cs, sn);
}

// ---------------- LayerNorm: fp32 X -> bf16 Xn ----------------
__global__ __launch_bounds__(256) void ln_kernel(const float* __restrict__ X,
    const float* __restrict__ w, const float* __restrict__ bta,
    short* __restrict__ Xn) {
  int row = blockIdx.x;
  int tid = threadIdx.x;
  const float* xr = X + (size_t)row * D_;
  float x[8];
  float4 v0 = *(const float4*)(xr + tid * 4);
  float4 v1 = *(const float4*)(xr + 1024 + tid * 4);
  x[0] = v0.x; x[1] = v0.y; x[2] = v0.z; x[3] = v0.w;
  x[4] = v1.x; x[5] = v1.y; x[6] = v1.z; x[7] = v1.w;
  float sum = 0.f, ssq = 0.f;
#pragma unroll
  for (int i = 0; i < 8; i++) { sum += x[i]; ssq += x[i] * x[i]; }
#pragma unroll
  for (int off = 1; off < 64; off <<= 1) {
    sum += __shfl_xor(sum, off, 64);
    ssq += __shfl_xor(ssq, off, 64);
  }
  __shared__ float s1[4], s2[4];
  int wave = tid >> 6;
  if ((tid & 63) == 0) { s1[wave] = sum; s2[wave] = ssq; }
  __syncthreads();
  sum = s1[0] + s1[1] + s1[2] + s1[3];
  ssq = s2[0] + s2[1] + s2[2] + s2[3];
  float mu = sum * (1.0f / D_);
  float var = ssq * (1.0f / D_) - mu * mu;
  float rs = rsqrtf(var + 1e-5f);
  short* orow = Xn + (size_t)row * D_;
#pragma unroll
  for (int i = 0; i < 8; i++) {
    int col = (i < 4) ? (tid * 4 + i) : (1024 + tid * 4 + (i - 4));
    float xn = (x[i] - mu) * rs * w[col] + bta[col];
    orow[col] = f2bf(xn);
  }
}

// ---------------- Transpose + cast: W (RxC fp32) -> WT (CxR bf16) ----------------
__global__ __launch_bounds__(256) void transpose_cvt(const float* __restrict__ W,
    short* __restrict__ WT, int R, int C) {
  __shared__ float t[32][33];
  int tx = threadIdx.x, ty = threadIdx.y;
  int c0 = blockIdx.x * 32, r0 = blockIdx.y * 32;
#pragma unroll
  for (int i = 0; i < 4; i++)
    t[ty + i * 8][tx] = W[(size_t)(r0 + ty + i * 8) * C + c0 + tx];
  __syncthreads();
#pragma unroll
  for (int i = 0; i < 4; i++)
    WT[(size_t)(c0 + ty + i * 8) * R + r0 + tx] = f2bf(t[tx][ty + i * 8]);
}

// ---------------- GEMM: 256x256 block, 8 waves (2Mx4N), BK=64 ----------------
// (unchanged from round 7 — register-double-buffered 4-cluster pipeline + manual
// counted lgkmcnt; LGKM counts C1:4 C2:8 C3:4 C4:8/0; vmcnt windows 6/4/0; XOR LDS
// swizzle conflict-free; T1 XCD swizzle.)
template<int EPI>
__global__ __launch_bounds__(512, 2) void gemm_bt(const short* __restrict__ A,
    const short* __restrict__ Bt, short* __restrict__ Cb, short* __restrict__ Vt,
    const float2* __restrict__ tab, float* __restrict__ Cf,
    const float* __restrict__ resid, int M, int N, int K) {
  __shared__ __align__(16) short lA[2][2][256][32];
  __shared__ __align__(16) short lB[2][2][256][32];
  int tid = threadIdx.x;
  int wave = tid >> 6, lane = tid & 63;
  int m16 = lane & 15, quad = lane >> 4;
  int wm = (wave >> 2) * 128, wn = (wave & 3) * 64;

  // T1 chunked XCD swizzle
  int bid = blockIdx.x;
  int q = bid & 7, c = bid >> 3;
  int xb = c >> 2;
  int yb = (q << 2) | (c & 3);
  int m0 = yb * 256, n0 = xb * 256;

  const ffrag4 fzero = {0.f, 0.f, 0.f, 0.f};
  ffrag4 acc[8][4];
#pragma unroll
  for (int i = 0; i < 8; i++)
#pragma unroll
    for (int j = 0; j < 4; j++) acc[i][j] = fzero;

  // ---- hoisted staging addresses (swizzle folded into the global source) ----
  int r0_ = tid >> 2;                                   // rows 0..127
  int csw = ((tid & 3) ^ ((r0_ >> 1) & 3)) << 3;        // swizzled 8-short chunk
  const short* gA0 = A + (size_t)(m0 + r0_) * K + csw;
  const short* gA1 = A + (size_t)(m0 + r0_ + 128) * K + csw;
  const short* gB0 = Bt + (size_t)(n0 + r0_) * K + csw;
  const short* gB1 = Bt + (size_t)(n0 + r0_ + 128) * K + csw;
  int ldW = wave << 10;                                 // byte offset of this wave's slab

  // stage half h of K-tile kt into buffer d: 2 GL16/thread, linear LDS dest
#define STG(g0, g1, larr, kt, h, d) { \
    const short* s0_ = (g0) + ((size_t)(kt) << 6) + ((h) << 5); \
    const short* s1_ = (g1) + ((size_t)(kt) << 6) + ((h) << 5); \
    char* dst_ = (char*)(larr) + (((d) << 15) | ((h) << 14)) + ldW; \
    GL16(s0_, dst_); \
    GL16(s1_, dst_ + 8192); }

  // ---- hoisted ds_read byte offsets within one [256][32] half ----
  unsigned offA[8], offB[4];
#pragma unroll
  for (int mi = 0; mi < 8; mi++) {
    int ra = wm + mi * 16 + m16;
    offA[mi] = (unsigned)(ra * 64 + ((quad ^ ((ra >> 1) & 3)) << 4));
  }
#pragma unroll
  for (int ni = 0; ni < 4; ni++) {
    int rb = wn + ni * 16 + m16;
    offB[ni] = (unsigned)(rb * 64 + ((quad ^ ((rb >> 1) & 3)) << 4));
  }
  unsigned aLds = LDSU(&lA[0][0][0][0]);
  unsigned bLds = LDSU(&lB[0][0][0][0]);

  bfrag8 afA[4], afB[4], bfA[4], bfB[4];

#define MF16(AF, BF, BASE) { \
    __builtin_amdgcn_s_setprio(1); \
    _Pragma("unroll") \
    for (int mi_ = 0; mi_ < 4; mi_++) \
      _Pragma("unroll") \
      for (int ni_ = 0; ni_ < 4; ni_++) \
        acc[(BASE) + mi_][ni_] = __builtin_amdgcn_mfma_f32_16x16x32_bf16( \
            AF[mi_], BF[ni_], acc[(BASE) + mi_][ni_], 0, 0, 0); \
    __builtin_amdgcn_s_setprio(0); }

#define KTILE(T, S1, S2) { \
    const int cur_ = (T) & 1, nxt_ = cur_ ^ 1; \
    const unsigned h0_ = (unsigned)(cur_ << 15); \
    const unsigned h1_ = h0_ | 16384u; \
    const unsigned g0_ = (unsigned)(nxt_ << 15); \
    /* C1 */ \
    BARRIER(); \
    afB[0] = DSR128(aLds + h0_ + offA[4]); \
    afB[1] = DSR128(aLds + h0_ + offA[5]); \
    afB[2] = DSR128(aLds + h0_ + offA[6]); \
    afB[3] = DSR128(aLds + h0_ + offA[7]); \
    if (S1) STG(gA0, gA1, lA, (T) + 1, 1, nxt_); \
    LGKM(4); \
    MF16(afA, bfA, 0); \
    if (S1) { VMW6(); } else { VMW0(); } \
    /* C2 */ \
    BARRIER(); \
    bfB[0] = DSR128(bLds + h1_ + offB[0]); \
    bfB[1] = DSR128(bLds + h1_ + offB[1]); \
    bfB[2] = DSR128(bLds + h1_ + offB[2]); \
    bfB[3] = DSR128(bLds + h1_ + offB[3]); \
    afA[0] = DSR128(aLds + h1_ + offA[0]); \
    afA[1] = DSR128(aLds + h1_ + offA[1]); \
    afA[2] = DSR128(aLds + h1_ + offA[2]); \
    afA[3] = DSR128(aLds + h1_ + offA[3]); \
    if (S1) STG(gB0, gB1, lB, (T) + 1, 1, nxt_); \
    LGKM(8); \
    MF16(afB, bfA, 4); \
    /* C3 */ \
    BARRIER(); \
    afB[0] = DSR128(aLds + h1_ + offA[4]); \
    afB[1] = DSR128(aLds + h1_ + offA[5]); \
    afB[2] = DSR128(aLds + h1_ + offA[6]); \
    afB[3] = DSR128(aLds + h1_ + offA[7]); \
    if (S2) STG(gA0, gA1, lA, (T) + 2, 0, cur_); \
    LGKM(4); \
    MF16(afA, bfB, 0); \
    if (S2) { VMW6(); } else if (S1) { VMW4(); } \
    /* C4 */ \
    BARRIER(); \
    if (S1) { \
      bfA[0] = DSR128(bLds + g0_ + offB[0]); \
      bfA[1] = DSR128(bLds + g0_ + offB[1]); \
      bfA[2] = DSR128(bLds + g0_ + offB[2]); \
      bfA[3] = DSR128(bLds + g0_ + offB[3]); \
      afA[0] = DSR128(aLds + g0_ + offA[0]); \
      afA[1] = DSR128(aLds + g0_ + offA[1]); \
      afA[2] = DSR128(aLds + g0_ + offA[2]); \
      afA[3] = DSR128(aLds + g0_ + offA[3]); \
    } \
    if (S2) STG(gB0, gB1, lB, (T) + 2, 0, cur_); \
    if (S1) { LGKM(8); } else { LGKM(0); } \
    MF16(afB, bfB, 4); \
  }

  // prologue
  STG(gA0, gA1, lA, 0, 0, 0); STG(gB0, gB1, lB, 0, 0, 0);
  STG(gA0, gA1, lA, 0, 1, 0); STG(gB0, gB1, lB, 0, 1, 0);
  STG(gA0, gA1, lA, 1, 0, 1); STG(gB0, gB1, lB, 1, 0, 1);
  VMW8();
  BARRIER();
  bfA[0] = DSR128(bLds + offB[0]);
  bfA[1] = DSR128(bLds + offB[1]);
  bfA[2] = DSR128(bLds + offB[2]);
  bfA[3] = DSR128(bLds + offB[3]);
  afA[0] = DSR128(aLds + offA[0]);
  afA[1] = DSR128(aLds + offA[1]);
  afA[2] = DSR128(aLds + offA[2]);
  afA[3] = DSR128(aLds + offA[3]);

  int nK = K >> 6;
  for (int t = 0; t < nK - 2; ++t) KTILE(t, 1, 1);
  KTILE(nK - 2, 1, 0);
  KTILE(nK - 1, 0, 0);
#undef KTILE
#undef MF16
#undef STG

  // ---- epilogue ----
#pragma unroll
  for (int mi = 0; mi < 8; mi++) {
    int rowb = m0 + wm + mi * 16 + quad * 4;
#pragma unroll
    for (int ni = 0; ni < 4; ni++) {
      int col = n0 + wn + ni * 16 + m16;
      if (EPI == 1) {
#pragma unroll
        for (int r = 0; r < 4; r++) {
          size_t idx = (size_t)(rowb + r) * N + col;
          Cf[idx] = acc[mi][ni][r] + resid[idx];
        }
      } else if (n0 >= 4096) {
        // V: direct store in Vt (b,h,Dh,S) layout, 4 consecutive s as short4
        int d = col - 4096;
        short4 pk;
        pk.x = f2bf(acc[mi][ni][0]);
        pk.y = f2bf(acc[mi][ni][1]);
        pk.z = f2bf(acc[mi][ni][2]);
        pk.w = f2bf(acc[mi][ni][3]);
        *(short4*)(Vt + ((size_t)((rowb >> 11) * H_ + (d >> 7)) * DH_ + (d & 127)) * S_ +
                   (rowb & (S_ - 1))) = pk;
      } else if ((col & 127) < 64) {
        // fused RoPE on Q/K via table
        int p = (col & 127) >> 1;
        float sgn = (col & 1) ? 1.0f : -1.0f;
#pragma unroll
        for (int r = 0; r < 4; r++) {
          float own = acc[mi][ni][r];
          float prt = __shfl_xor(own, 1, 64);
          float2 cssn = tab[((rowb + r) & (S_ - 1)) * 32 + p];
          Cb[(size_t)(rowb + r) * QKS_ + col] = f2bf(own * cssn.x + sgn * prt * cssn.y);
        }
      } else {
#pragma unroll
        for (int r = 0; r < 4; r++)
          Cb[(size_t)(rowb + r) * QKS_ + col] = f2bf(acc[mi][ni][r]);
      }
    }
  }
}

// ---------------- Flash attention, S^T form ----------------
// ROUND-8: (1) XCD-aware 1-D grid (bijective for 512 blocks): all 8 q-chunk blocks
// sharing one (b,h)'s K/V stream land on the same XCD -> K/V L2-resident (FETCH was
// 278 MB vs ~96 MB unique). (2) pk2 -> v_cvt_pk_bf16_f32 (1 instr vs ~7; RNE matches).
// (3) s_setprio(1) around QK^T and PV MFMA clusters (T5).
__global__ __launch_bounds__(512) void attn_kernel(const short* __restrict__ qkv,
    const short* __restrict__ Vt, short* __restrict__ ctx) {
  __shared__ __align__(16) short lK[2][64 * 128];   // [key][d]  16 KiB each
  __shared__ __align__(16) short lV[2][128 * 64];   // [d][key]  16 KiB each
  int tid = threadIdx.x;
  int wave = tid >> 6, lane = tid & 63;
  int m16 = lane & 15, quad = lane >> 4;
  // XCD swizzle: bid%8 = XCD (HW round-robin); bh%8 == XCD so K/V of one head stays
  // on one XCD's L2; qchunk = c>>3 covers the 8 q-chunks of that head on the same XCD.
  int bid = blockIdx.x;
  int xcd = bid & 7, c = bid >> 3;
  int bh = ((c & 7) << 3) | xcd;
  int qchunk = c >> 3;
  int b = bh >> 4, h = bh & 15;
  int qbase = qchunk * 256 + wave * 32;

  const float qscale = 1.4426950408889634f * 0.08838834764831845f;
  bfrag8 qf[2][4];
#pragma unroll
  for (int qb = 0; qb < 2; qb++)
#pragma unroll
    for (int kc = 0; kc < 4; kc++) {
      bfrag8 q = *(const bfrag8*)(qkv +
          (size_t)(b * S_ + qbase + qb * 16 + m16) * QKS_ + h * DH_ + kc * 32 + quad * 8);
#pragma unroll
      for (int j = 0; j < 8; j++) q[j] = f2bf(bf2f(q[j]) * qscale);
      qf[qb][kc] = q;
    }

  const ffrag4 fzero = {0.f, 0.f, 0.f, 0.f};
  ffrag4 oacc[2][8];
#pragma unroll
  for (int qb = 0; qb < 2; qb++)
#pragma unroll
    for (int nd = 0; nd < 8; nd++) oacc[qb][nd] = fzero;
  float lpart[2] = {0.f, 0.f};

  int krow = lane >> 4;
  int kcb = lane & 15;
  int vrow = lane >> 3;
  int vcb = lane & 7;

  {
#pragma unroll
    for (int i = 0; i < 2; i++) {
      int c2 = wave + i * 8;
      int r = c2 * 4 + krow;
      int sb = kcb ^ (r & 15);
      GL16(qkv + (size_t)(b * S_ + r) * QKS_ + D_ + h * DH_ + sb * 8, &lK[0][c2 * 512]);
    }
#pragma unroll
    for (int i = 0; i < 2; i++) {
      int c2 = wave + i * 8;
      int r = c2 * 8 + vrow;
      int sb = vcb ^ (r & 7);
      GL16(Vt + (size_t)(bh * DH_ + r) * S_ + sb * 8, &lV[0][c2 * 512]);
    }
  }
  __syncthreads();

  for (int kt = 0; kt < 32; kt++) {
    int cur = kt & 1;
    if (kt < 31) {
      int sk0 = (kt + 1) * 64;
      int nb = cur ^ 1;
#pragma unroll
      for (int i = 0; i < 2; i++) {
        int c2 = wave + i * 8;
        int r = c2 * 4 + krow;
        int sb = kcb ^ (r & 15);
        GL16(qkv + (size_t)(b * S_ + sk0 + r) * QKS_ + D_ + h * DH_ + sb * 8, &lK[nb][c2 * 512]);
      }
#pragma unroll
      for (int i = 0; i < 2; i++) {
        int c2 = wave + i * 8;
        int r = c2 * 8 + vrow;
        int sb = vcb ^ (r & 7);
        GL16(Vt + (size_t)(bh * DH_ + r) * S_ + sk0 + sb * 8, &lV[nb][c2 * 512]);
      }
    }

    const short* kb = &lK[cur][0];
    const short* vb = &lV[cur][0];

    ffrag4 sacc[2][4];
#pragma unroll
    for (int qb = 0; qb < 2; qb++)
#pragma unroll
      for (int ntk = 0; ntk < 4; ntk++) sacc[qb][ntk] = fzero;
    __builtin_amdgcn_s_setprio(1);
#pragma unroll
    for (int ntk = 0; ntk < 4; ntk++)
#pragma unroll
      for (int kc = 0; kc < 4; kc++) {
        bfrag8 kf = *(const bfrag8*)(kb + (ntk * 16 + m16) * 128 +
                                     (((kc * 4 + quad) ^ m16) << 3));
        sacc[0][ntk] = __builtin_amdgcn_mfma_f32_16x16x32_bf16(kf, qf[0][kc], sacc[0][ntk], 0, 0, 0);
        sacc[1][ntk] = __builtin_amdgcn_mfma_f32_16x16x32_bf16(kf, qf[1][kc], sacc[1][ntk], 0, 0, 0);
      }
    __builtin_amdgcn_s_setprio(0);

    bfrag8 pA[2][2];
#pragma unroll
    for (int qb = 0; qb < 2; qb++) {
      unsigned Xp[4][2];
      float ls = 0.f;
#pragma unroll
      for (int ntk = 0; ntk < 4; ntk++) {
        float e0 = exp2f(sacc[qb][ntk][0]);
        float e1 = exp2f(sacc[qb][ntk][1]);
        float e2 = exp2f(sacc[qb][ntk][2]);
        float e3 = exp2f(sacc[qb][ntk][3]);
        ls += (e0 + e1) + (e2 + e3);
        Xp[ntk][0] = cvtpk(e0, e1);
        Xp[ntk][1] = cvtpk(e2, e3);
      }
      lpart[qb] += ls;
#pragma unroll
      for (int kc = 0; kc < 2; kc++) {
        unsigned x0 = Xp[2 * kc][0], x1 = Xp[2 * kc][1];
        unsigned y0 = Xp[2 * kc + 1][0], y1 = Xp[2 * kc + 1][1];
        asm("v_permlane32_swap_b32 %0, %1" : "+v"(x0), "+v"(y0));
        asm("v_permlane16_swap_b32 %0, %1" : "+v"(x0), "+v"(y0));
        asm("v_permlane32_swap_b32 %0, %1" : "+v"(x1), "+v"(y1));
        asm("v_permlane16_swap_b32 %0, %1" : "+v"(x1), "+v"(y1));
        union { int4 i4; bfrag8 b8; } u;
        u.i4 = (int4){(int)x0, (int)x1, (int)y0, (int)y1};
        pA[qb][kc] = u.b8;
      }
    }

    __builtin_amdgcn_s_setprio(1);
#pragma unroll
    for (int kc = 0; kc < 2; kc++)
#pragma unroll
      for (int nd = 0; nd < 8; nd++) {
        bfrag8 vf = *(const bfrag8*)(vb + (nd * 16 + m16) * 64 +
                                     (((kc * 4 + quad) ^ (m16 & 7)) << 3));
        oacc[0][nd] = __builtin_amdgcn_mfma_f32_16x16x32_bf16(pA[0][kc], vf, oacc[0][nd], 0, 0, 0);
        oacc[1][nd] = __builtin_amdgcn_mfma_f32_16x16x32_bf16(pA[1][kc], vf, oacc[1][nd], 0, 0, 0);
      }
    __builtin_amdgcn_s_setprio(0);

    __syncthreads();
  }

#pragma unroll
  for (int qb = 0; qb < 2; qb++) {
    lpart[qb] += __shfl_xor(lpart[qb], 16, 64);
    lpart[qb] += __shfl_xor(lpart[qb], 32, 64);
  }
#pragma unroll
  for (int qb = 0; qb < 2; qb++) {
    float inv[4];
#pragma unroll
    for (int r = 0; r < 4; r++) inv[r] = 1.0f / __shfl(lpart[qb], quad * 4 + r, 64);
#pragma unroll
    for (int nd = 0; nd < 8; nd++)
#pragma unroll
      for (int r = 0; r < 4; r++) {
        int row = qbase + qb * 16 + quad * 4 + r;
        int col = h * DH_ + nd * 16 + m16;
        ctx[(size_t)(b * S_ + row) * D_ + col] = f2bf(oacc[qb][nd][r] * inv[r]);
      }
  }
}

// ---------------- launch ----------------
extern "C" void kernel_launch(void* const* d_in, const int* in_sizes, int n_in,
                              void* d_out, int out_size, void* d_ws, size_t ws_size,
                              hipStream_t stream) {
  const float* X    = (const float*)d_in[0];
  const float* lnw  = (const float*)d_in[1];
  const float* lnb  = (const float*)d_in[2];
  const float* Win  = (const float*)d_in[3];
  const float* Wout = (const float*)d_in[4];
  float* out = (float*)d_out;
  char* ws = (char*)d_ws;
  short*  Xn    = (short*)(ws + 0);          //  32 MiB: 8192x2048 bf16
  short*  WinT  = (short*)(ws + 33554432);   //  24 MiB: 6144x2048 bf16
  short*  WoutT = (short*)(ws + 58720256);   //   8 MiB: 2048x2048 bf16
  short*  qkv   = (short*)(ws + 67108864);   //  64 MiB: 8192x4096 bf16 (Q,K only)
  short*  Vt    = (short*)(ws + 134217728);  //  32 MiB: (b,h,128,2048) bf16
  short*  ctx   = (short*)(ws + 167772160);  //  32 MiB: 8192x2048 bf16
  float2* tab   = (float2*)(ws + 201326592); // 512 KiB: 2048x32 cos/sin

  rope_tab_kernel<<<256, 256, 0, stream>>>(tab);
  transpose_cvt<<<dim3(192, 64), dim3(32, 8), 0, stream>>>(Win, WinT, 2048, 6144);
  transpose_cvt<<<dim3(64, 64), dim3(32, 8), 0, stream>>>(Wout, WoutT, 2048, 2048);
  ln_kernel<<<8192, 256, 0, stream>>>(X, lnw, lnb, Xn);
  gemm_bt<0><<<768, 512, 0, stream>>>(Xn, WinT, qkv, Vt, tab, nullptr, nullptr, 8192, 6144, 2048);
  attn_kernel<<<512, 512, 0, stream>>>(qkv, Vt, ctx);
  gemm_bt<1><<<256, 512, 0, stream>>>(ctx, WoutT, nullptr, nullptr, nullptr, out, X, 8192, 2048, 2048);
}

// Round 9
// 615.115 us; speedup vs baseline: 1.0576x; 1.0334x over previous
//
#include <hip/hip_runtime.h>
#include <hip/hip_bf16.h>
#include <cstddef>

#define B_ 4
#define S_ 2048
#define D_ 2048
#define H_ 16
#define DH_ 128
#define QKS_ 4096

typedef __attribute__((ext_vector_type(8))) short bfrag8;
typedef __attribute__((ext_vector_type(4))) float ffrag4;
typedef __attribute__((ext_vector_type(4))) int ifrag4;

typedef const __attribute__((address_space(1))) void* gptr1;
typedef __attribute__((address_space(3))) void* lptr3;
#define GL16(g, l) __builtin_amdgcn_global_load_lds((gptr1)(g), (lptr3)(l), 16, 0, 0)
#define LDSU(p) ((unsigned)(unsigned long long)(lptr3)(p))

#define BARRIER() { asm volatile("" ::: "memory"); __builtin_amdgcn_s_barrier(); asm volatile("" ::: "memory"); }
#define VMW8() asm volatile("s_waitcnt vmcnt(8)" ::: "memory")
#define VMW6() asm volatile("s_waitcnt vmcnt(6)" ::: "memory")
#define VMW4() asm volatile("s_waitcnt vmcnt(4)" ::: "memory")
#define VMW0() asm volatile("s_waitcnt vmcnt(0)" ::: "memory")
// Counted lgkm wait + scheduler fence (rule 18): MFMA after this waits only for reads
// OLDER than the N newest outstanding DS ops.
#define LGKM(n) { asm volatile("s_waitcnt lgkmcnt(" #n ")" ::: "memory"); __builtin_amdgcn_sched_barrier(0); }

// inline-asm ds_read_b128 from a 32-bit LDS byte address; stays outstanding until a
// counted lgkmcnt drains it.
__device__ __forceinline__ bfrag8 DSR128(unsigned a) {
  ifrag4 r;
  asm volatile("ds_read_b128 %0, %1" : "=v"(r) : "v"(a));
  return __builtin_bit_cast(bfrag8, r);
}

__device__ __forceinline__ short f2bf(float f) {
  unsigned u = __float_as_uint(f);
  u = (u + 0x7FFFu + ((u >> 16) & 1u)) >> 16;
  return (short)u;
}
__device__ __forceinline__ float bf2f(short s) {
  return __uint_as_float(((unsigned)(unsigned short)s) << 16);
}
// HW packed f32->bf16x2 (RNE), 1 instr vs ~7 for the manual round (T12 primitive).
__device__ __forceinline__ unsigned cvtpk(float lo, float hi) {
  unsigned r;
  asm("v_cvt_pk_bf16_f32 %0, %1, %2" : "=v"(r) : "v"(lo), "v"(hi));
  return r;
}

// ---------------- RoPE cos/sin table: tab[s*32+p] = {cos,sin}(s * 10000^(-2p/64)) ----------------
__global__ __launch_bounds__(256) void rope_tab_kernel(float2* __restrict__ tab) {
  int idx = blockIdx.x * 256 + threadIdx.x;   // 65536
  int s = idx >> 5, p = idx & 31;
  float invf = exp2f(-(float)p * (13.287712379549449f / 32.0f));
  float sn, cs;
  sincosf((float)s * invf, &sn, &cs);
  tab[idx] = make_float2(cs, sn);
}

// ---------------- LayerNorm: fp32 X -> bf16 Xn ----------------
__global__ __launch_bounds__(256) void ln_kernel(const float* __restrict__ X,
    const float* __restrict__ w, const float* __restrict__ bta,
    short* __restrict__ Xn) {
  int row = blockIdx.x;
  int tid = threadIdx.x;
  const float* xr = X + (size_t)row * D_;
  float x[8];
  float4 v0 = *(const float4*)(xr + tid * 4);
  float4 v1 = *(const float4*)(xr + 1024 + tid * 4);
  x[0] = v0.x; x[1] = v0.y; x[2] = v0.z; x[3] = v0.w;
  x[4] = v1.x; x[5] = v1.y; x[6] = v1.z; x[7] = v1.w;
  float sum = 0.f, ssq = 0.f;
#pragma unroll
  for (int i = 0; i < 8; i++) { sum += x[i]; ssq += x[i] * x[i]; }
#pragma unroll
  for (int off = 1; off < 64; off <<= 1) {
    sum += __shfl_xor(sum, off, 64);
    ssq += __shfl_xor(ssq, off, 64);
  }
  __shared__ float s1[4], s2[4];
  int wave = tid >> 6;
  if ((tid & 63) == 0) { s1[wave] = sum; s2[wave] = ssq; }
  __syncthreads();
  sum = s1[0] + s1[1] + s1[2] + s1[3];
  ssq = s2[0] + s2[1] + s2[2] + s2[3];
  float mu = sum * (1.0f / D_);
  float var = ssq * (1.0f / D_) - mu * mu;
  float rs = rsqrtf(var + 1e-5f);
  short* orow = Xn + (size_t)row * D_;
#pragma unroll
  for (int i = 0; i < 8; i++) {
    int col = (i < 4) ? (tid * 4 + i) : (1024 + tid * 4 + (i - 4));
    float xn = (x[i] - mu) * rs * w[col] + bta[col];
    orow[col] = f2bf(xn);
  }
}

// ---------------- Transpose + cast: W (RxC fp32) -> WT (CxR bf16) ----------------
__global__ __launch_bounds__(256) void transpose_cvt(const float* __restrict__ W,
    short* __restrict__ WT, int R, int C) {
  __shared__ float t[32][33];
  int tx = threadIdx.x, ty = threadIdx.y;
  int c0 = blockIdx.x * 32, r0 = blockIdx.y * 32;
#pragma unroll
  for (int i = 0; i < 4; i++)
    t[ty + i * 8][tx] = W[(size_t)(r0 + ty + i * 8) * C + c0 + tx];
  __syncthreads();
#pragma unroll
  for (int i = 0; i < 4; i++)
    WT[(size_t)(c0 + ty + i * 8) * R + r0 + tx] = f2bf(t[tx][ty + i * 8]);
}

// ---------------- GEMM: 256x256 block, 8 waves (2Mx4N), BK=64 ----------------
// (unchanged from round 8 — register-double-buffered 4-cluster pipeline + manual
// counted lgkmcnt; LGKM counts C1:4 C2:8 C3:4 C4:8/0; vmcnt windows 6/4/0; XOR LDS
// swizzle conflict-free; T1 XCD swizzle.)
template<int EPI>
__global__ __launch_bounds__(512, 2) void gemm_bt(const short* __restrict__ A,
    const short* __restrict__ Bt, short* __restrict__ Cb, short* __restrict__ Vt,
    const float2* __restrict__ tab, float* __restrict__ Cf,
    const float* __restrict__ resid, int M, int N, int K) {
  __shared__ __align__(16) short lA[2][2][256][32];
  __shared__ __align__(16) short lB[2][2][256][32];
  int tid = threadIdx.x;
  int wave = tid >> 6, lane = tid & 63;
  int m16 = lane & 15, quad = lane >> 4;
  int wm = (wave >> 2) * 128, wn = (wave & 3) * 64;

  // T1 chunked XCD swizzle
  int bid = blockIdx.x;
  int q = bid & 7, c = bid >> 3;
  int xb = c >> 2;
  int yb = (q << 2) | (c & 3);
  int m0 = yb * 256, n0 = xb * 256;

  const ffrag4 fzero = {0.f, 0.f, 0.f, 0.f};
  ffrag4 acc[8][4];
#pragma unroll
  for (int i = 0; i < 8; i++)
#pragma unroll
    for (int j = 0; j < 4; j++) acc[i][j] = fzero;

  // ---- hoisted staging addresses (swizzle folded into the global source) ----
  int r0_ = tid >> 2;                                   // rows 0..127
  int csw = ((tid & 3) ^ ((r0_ >> 1) & 3)) << 3;        // swizzled 8-short chunk
  const short* gA0 = A + (size_t)(m0 + r0_) * K + csw;
  const short* gA1 = A + (size_t)(m0 + r0_ + 128) * K + csw;
  const short* gB0 = Bt + (size_t)(n0 + r0_) * K + csw;
  const short* gB1 = Bt + (size_t)(n0 + r0_ + 128) * K + csw;
  int ldW = wave << 10;                                 // byte offset of this wave's slab

  // stage half h of K-tile kt into buffer d: 2 GL16/thread, linear LDS dest
#define STG(g0, g1, larr, kt, h, d) { \
    const short* s0_ = (g0) + ((size_t)(kt) << 6) + ((h) << 5); \
    const short* s1_ = (g1) + ((size_t)(kt) << 6) + ((h) << 5); \
    char* dst_ = (char*)(larr) + (((d) << 15) | ((h) << 14)) + ldW; \
    GL16(s0_, dst_); \
    GL16(s1_, dst_ + 8192); }

  // ---- hoisted ds_read byte offsets within one [256][32] half ----
  unsigned offA[8], offB[4];
#pragma unroll
  for (int mi = 0; mi < 8; mi++) {
    int ra = wm + mi * 16 + m16;
    offA[mi] = (unsigned)(ra * 64 + ((quad ^ ((ra >> 1) & 3)) << 4));
  }
#pragma unroll
  for (int ni = 0; ni < 4; ni++) {
    int rb = wn + ni * 16 + m16;
    offB[ni] = (unsigned)(rb * 64 + ((quad ^ ((rb >> 1) & 3)) << 4));
  }
  unsigned aLds = LDSU(&lA[0][0][0][0]);
  unsigned bLds = LDSU(&lB[0][0][0][0]);

  bfrag8 afA[4], afB[4], bfA[4], bfB[4];

#define MF16(AF, BF, BASE) { \
    __builtin_amdgcn_s_setprio(1); \
    _Pragma("unroll") \
    for (int mi_ = 0; mi_ < 4; mi_++) \
      _Pragma("unroll") \
      for (int ni_ = 0; ni_ < 4; ni_++) \
        acc[(BASE) + mi_][ni_] = __builtin_amdgcn_mfma_f32_16x16x32_bf16( \
            AF[mi_], BF[ni_], acc[(BASE) + mi_][ni_], 0, 0, 0); \
    __builtin_amdgcn_s_setprio(0); }

#define KTILE(T, S1, S2) { \
    const int cur_ = (T) & 1, nxt_ = cur_ ^ 1; \
    const unsigned h0_ = (unsigned)(cur_ << 15); \
    const unsigned h1_ = h0_ | 16384u; \
    const unsigned g0_ = (unsigned)(nxt_ << 15); \
    /* C1 */ \
    BARRIER(); \
    afB[0] = DSR128(aLds + h0_ + offA[4]); \
    afB[1] = DSR128(aLds + h0_ + offA[5]); \
    afB[2] = DSR128(aLds + h0_ + offA[6]); \
    afB[3] = DSR128(aLds + h0_ + offA[7]); \
    if (S1) STG(gA0, gA1, lA, (T) + 1, 1, nxt_); \
    LGKM(4); \
    MF16(afA, bfA, 0); \
    if (S1) { VMW6(); } else { VMW0(); } \
    /* C2 */ \
    BARRIER(); \
    bfB[0] = DSR128(bLds + h1_ + offB[0]); \
    bfB[1] = DSR128(bLds + h1_ + offB[1]); \
    bfB[2] = DSR128(bLds + h1_ + offB[2]); \
    bfB[3] = DSR128(bLds + h1_ + offB[3]); \
    afA[0] = DSR128(aLds + h1_ + offA[0]); \
    afA[1] = DSR128(aLds + h1_ + offA[1]); \
    afA[2] = DSR128(aLds + h1_ + offA[2]); \
    afA[3] = DSR128(aLds + h1_ + offA[3]); \
    if (S1) STG(gB0, gB1, lB, (T) + 1, 1, nxt_); \
    LGKM(8); \
    MF16(afB, bfA, 4); \
    /* C3 */ \
    BARRIER(); \
    afB[0] = DSR128(aLds + h1_ + offA[4]); \
    afB[1] = DSR128(aLds + h1_ + offA[5]); \
    afB[2] = DSR128(aLds + h1_ + offA[6]); \
    afB[3] = DSR128(aLds + h1_ + offA[7]); \
    if (S2) STG(gA0, gA1, lA, (T) + 2, 0, cur_); \
    LGKM(4); \
    MF16(afA, bfB, 0); \
    if (S2) { VMW6(); } else if (S1) { VMW4(); } \
    /* C4 */ \
    BARRIER(); \
    if (S1) { \
      bfA[0] = DSR128(bLds + g0_ + offB[0]); \
      bfA[1] = DSR128(bLds + g0_ + offB[1]); \
      bfA[2] = DSR128(bLds + g0_ + offB[2]); \
      bfA[3] = DSR128(bLds + g0_ + offB[3]); \
      afA[0] = DSR128(aLds + g0_ + offA[0]); \
      afA[1] = DSR128(aLds + g0_ + offA[1]); \
      afA[2] = DSR128(aLds + g0_ + offA[2]); \
      afA[3] = DSR128(aLds + g0_ + offA[3]); \
    } \
    if (S2) STG(gB0, gB1, lB, (T) + 2, 0, cur_); \
    if (S1) { LGKM(8); } else { LGKM(0); } \
    MF16(afB, bfB, 4); \
  }

  // prologue
  STG(gA0, gA1, lA, 0, 0, 0); STG(gB0, gB1, lB, 0, 0, 0);
  STG(gA0, gA1, lA, 0, 1, 0); STG(gB0, gB1, lB, 0, 1, 0);
  STG(gA0, gA1, lA, 1, 0, 1); STG(gB0, gB1, lB, 1, 0, 1);
  VMW8();
  BARRIER();
  bfA[0] = DSR128(bLds + offB[0]);
  bfA[1] = DSR128(bLds + offB[1]);
  bfA[2] = DSR128(bLds + offB[2]);
  bfA[3] = DSR128(bLds + offB[3]);
  afA[0] = DSR128(aLds + offA[0]);
  afA[1] = DSR128(aLds + offA[1]);
  afA[2] = DSR128(aLds + offA[2]);
  afA[3] = DSR128(aLds + offA[3]);

  int nK = K >> 6;
  for (int t = 0; t < nK - 2; ++t) KTILE(t, 1, 1);
  KTILE(nK - 2, 1, 0);
  KTILE(nK - 1, 0, 0);
#undef KTILE
#undef MF16
#undef STG

  // ---- epilogue ----
#pragma unroll
  for (int mi = 0; mi < 8; mi++) {
    int rowb = m0 + wm + mi * 16 + quad * 4;
#pragma unroll
    for (int ni = 0; ni < 4; ni++) {
      int col = n0 + wn + ni * 16 + m16;
      if (EPI == 1) {
#pragma unroll
        for (int r = 0; r < 4; r++) {
          size_t idx = (size_t)(rowb + r) * N + col;
          Cf[idx] = acc[mi][ni][r] + resid[idx];
        }
      } else if (n0 >= 4096) {
        // V: direct store in Vt (b,h,Dh,S) layout, 4 consecutive s as short4
        int d = col - 4096;
        short4 pk;
        pk.x = f2bf(acc[mi][ni][0]);
        pk.y = f2bf(acc[mi][ni][1]);
        pk.z = f2bf(acc[mi][ni][2]);
        pk.w = f2bf(acc[mi][ni][3]);
        *(short4*)(Vt + ((size_t)((rowb >> 11) * H_ + (d >> 7)) * DH_ + (d & 127)) * S_ +
                   (rowb & (S_ - 1))) = pk;
      } else if ((col & 127) < 64) {
        // fused RoPE on Q/K via table
        int p = (col & 127) >> 1;
        float sgn = (col & 1) ? 1.0f : -1.0f;
#pragma unroll
        for (int r = 0; r < 4; r++) {
          float own = acc[mi][ni][r];
          float prt = __shfl_xor(own, 1, 64);
          float2 cssn = tab[((rowb + r) & (S_ - 1)) * 32 + p];
          Cb[(size_t)(rowb + r) * QKS_ + col] = f2bf(own * cssn.x + sgn * prt * cssn.y);
        }
      } else {
#pragma unroll
        for (int r = 0; r < 4; r++)
          Cb[(size_t)(rowb + r) * QKS_ + col] = f2bf(acc[mi][ni][r]);
      }
    }
  }
}

// ---------------- Flash attention, S^T form ----------------
// ROUND-9: 4-wave (256-thread) blocks, grid 1024, 2 blocks/CU. Register budget
// (~190/thread incl. unified AGPRs) caps at 2 waves/SIMD; with 512-thread blocks
// that meant ONE block/CU -> every __syncthreads (w/ implicit vmcnt drain) stalled
// the whole CU. Two co-resident 4-wave blocks have independent barriers -> one
// block computes while the other drains/stages. LDS layout, inner math, XCD
// swizzle (re-derived bijectively for 1024: bh%8==XCD), cvtpk, setprio unchanged.
// Staging addresses hoisted to 8 per-thread pointers += const stride per K-tile.
__global__ __launch_bounds__(256) void attn_kernel(const short* __restrict__ qkv,
    const short* __restrict__ Vt, short* __restrict__ ctx) {
  __shared__ __align__(16) short lK[2][64 * 128];   // [key][d]  16 KiB each
  __shared__ __align__(16) short lV[2][128 * 64];   // [d][key]  16 KiB each
  int tid = threadIdx.x;
  int wave = tid >> 6, lane = tid & 63;   // wave 0..3
  int m16 = lane & 15, quad = lane >> 4;
  // XCD swizzle (bijective for 1024 blocks): bid%8 = XCD; bh%8 == XCD so one head's
  // K/V stream stays on one XCD's L2; 16 q-chunk blocks of that head share it.
  int bid = blockIdx.x;
  int xcd = bid & 7, c = bid >> 3;        // c: 0..127
  int bh = ((c & 7) << 3) | xcd;          // 0..63
  int qchunk = c >> 3;                    // 0..15
  int b = bh >> 4, h = bh & 15;
  int qbase = qchunk * 128 + wave * 32;

  const float qscale = 1.4426950408889634f * 0.08838834764831845f;
  bfrag8 qf[2][4];
#pragma unroll
  for (int qb = 0; qb < 2; qb++)
#pragma unroll
    for (int kc = 0; kc < 4; kc++) {
      bfrag8 q = *(const bfrag8*)(qkv +
          (size_t)(b * S_ + qbase + qb * 16 + m16) * QKS_ + h * DH_ + kc * 32 + quad * 8);
#pragma unroll
      for (int j = 0; j < 8; j++) q[j] = f2bf(bf2f(q[j]) * qscale);
      qf[qb][kc] = q;
    }

  const ffrag4 fzero = {0.f, 0.f, 0.f, 0.f};
  ffrag4 oacc[2][8];
#pragma unroll
  for (int qb = 0; qb < 2; qb++)
#pragma unroll
    for (int nd = 0; nd < 8; nd++) oacc[qb][nd] = fzero;
  float lpart[2] = {0.f, 0.f};

  int krow = lane >> 4;
  int kcb = lane & 15;
  int vrow = lane >> 3;
  int vcb = lane & 7;

  // hoisted staging pointers: 4 K-chunks + 4 V-chunks per thread (i indexed by
  // compile-time constants only -> registers, rule 20). Advance by const per kt.
  const short* kp[4];
  const short* vp[4];
#pragma unroll
  for (int i = 0; i < 4; i++) {
    int c2 = wave + i * 4;                 // chunk 0..15
    int rK = c2 * 4 + krow;
    int sbK = kcb ^ (rK & 15);
    kp[i] = qkv + (size_t)(b * S_ + rK) * QKS_ + D_ + h * DH_ + sbK * 8;
    int rV = c2 * 8 + vrow;
    int sbV = vcb ^ (rV & 7);
    vp[i] = Vt + (size_t)(bh * DH_ + rV) * S_ + sbV * 8;
  }
  const size_t KSTEP = (size_t)64 * QKS_;  // shorts per K-tile (64 key rows)
  // V advances 64 keys = 64 shorts along S.

  // initial stage into buffer 0
#pragma unroll
  for (int i = 0; i < 4; i++) GL16(kp[i], &lK[0][(wave + i * 4) * 512]);
#pragma unroll
  for (int i = 0; i < 4; i++) GL16(vp[i], &lV[0][(wave + i * 4) * 512]);
  __syncthreads();

  for (int kt = 0; kt < 32; kt++) {
    int cur = kt & 1;
    if (kt < 31) {
      int nb = cur ^ 1;
#pragma unroll
      for (int i = 0; i < 4; i++) {
        kp[i] += KSTEP;
        GL16(kp[i], &lK[nb][(wave + i * 4) * 512]);
      }
#pragma unroll
      for (int i = 0; i < 4; i++) {
        vp[i] += 64;
        GL16(vp[i], &lV[nb][(wave + i * 4) * 512]);
      }
    }

    const short* kb = &lK[cur][0];
    const short* vb = &lV[cur][0];

    ffrag4 sacc[2][4];
#pragma unroll
    for (int qb = 0; qb < 2; qb++)
#pragma unroll
      for (int ntk = 0; ntk < 4; ntk++) sacc[qb][ntk] = fzero;
    __builtin_amdgcn_s_setprio(1);
#pragma unroll
    for (int ntk = 0; ntk < 4; ntk++)
#pragma unroll
      for (int kc = 0; kc < 4; kc++) {
        bfrag8 kf = *(const bfrag8*)(kb + (ntk * 16 + m16) * 128 +
                                     (((kc * 4 + quad) ^ m16) << 3));
        sacc[0][ntk] = __builtin_amdgcn_mfma_f32_16x16x32_bf16(kf, qf[0][kc], sacc[0][ntk], 0, 0, 0);
        sacc[1][ntk] = __builtin_amdgcn_mfma_f32_16x16x32_bf16(kf, qf[1][kc], sacc[1][ntk], 0, 0, 0);
      }
    __builtin_amdgcn_s_setprio(0);

    bfrag8 pA[2][2];
#pragma unroll
    for (int qb = 0; qb < 2; qb++) {
      unsigned Xp[4][2];
      float ls = 0.f;
#pragma unroll
      for (int ntk = 0; ntk < 4; ntk++) {
        float e0 = exp2f(sacc[qb][ntk][0]);
        float e1 = exp2f(sacc[qb][ntk][1]);
        float e2 = exp2f(sacc[qb][ntk][2]);
        float e3 = exp2f(sacc[qb][ntk][3]);
        ls += (e0 + e1) + (e2 + e3);
        Xp[ntk][0] = cvtpk(e0, e1);
        Xp[ntk][1] = cvtpk(e2, e3);
      }
      lpart[qb] += ls;
#pragma unroll
      for (int kc = 0; kc < 2; kc++) {
        unsigned x0 = Xp[2 * kc][0], x1 = Xp[2 * kc][1];
        unsigned y0 = Xp[2 * kc + 1][0], y1 = Xp[2 * kc + 1][1];
        asm("v_permlane32_swap_b32 %0, %1" : "+v"(x0), "+v"(y0));
        asm("v_permlane16_swap_b32 %0, %1" : "+v"(x0), "+v"(y0));
        asm("v_permlane32_swap_b32 %0, %1" : "+v"(x1), "+v"(y1));
        asm("v_permlane16_swap_b32 %0, %1" : "+v"(x1), "+v"(y1));
        union { int4 i4; bfrag8 b8; } u;
        u.i4 = (int4){(int)x0, (int)x1, (int)y0, (int)y1};
        pA[qb][kc] = u.b8;
      }
    }

    __builtin_amdgcn_s_setprio(1);
#pragma unroll
    for (int kc = 0; kc < 2; kc++)
#pragma unroll
      for (int nd = 0; nd < 8; nd++) {
        bfrag8 vf = *(const bfrag8*)(vb + (nd * 16 + m16) * 64 +
                                     (((kc * 4 + quad) ^ (m16 & 7)) << 3));
        oacc[0][nd] = __builtin_amdgcn_mfma_f32_16x16x32_bf16(pA[0][kc], vf, oacc[0][nd], 0, 0, 0);
        oacc[1][nd] = __builtin_amdgcn_mfma_f32_16x16x32_bf16(pA[1][kc], vf, oacc[1][nd], 0, 0, 0);
      }
    __builtin_amdgcn_s_setprio(0);

    __syncthreads();
  }

#pragma unroll
  for (int qb = 0; qb < 2; qb++) {
    lpart[qb] += __shfl_xor(lpart[qb], 16, 64);
    lpart[qb] += __shfl_xor(lpart[qb], 32, 64);
  }
#pragma unroll
  for (int qb = 0; qb < 2; qb++) {
    float inv[4];
#pragma unroll
    for (int r = 0; r < 4; r++) inv[r] = 1.0f / __shfl(lpart[qb], quad * 4 + r, 64);
#pragma unroll
    for (int nd = 0; nd < 8; nd++)
#pragma unroll
      for (int r = 0; r < 4; r++) {
        int row = qbase + qb * 16 + quad * 4 + r;
        int col = h * DH_ + nd * 16 + m16;
        ctx[(size_t)(b * S_ + row) * D_ + col] = f2bf(oacc[qb][nd][r] * inv[r]);
      }
  }
}

// ---------------- launch ----------------
extern "C" void kernel_launch(void* const* d_in, const int* in_sizes, int n_in,
                              void* d_out, int out_size, void* d_ws, size_t ws_size,
                              hipStream_t stream) {
  const float* X    = (const float*)d_in[0];
  const float* lnw  = (const float*)d_in[1];
  const float* lnb  = (const float*)d_in[2];
  const float* Win  = (const float*)d_in[3];
  const float* Wout = (const float*)d_in[4];
  float* out = (float*)d_out;
  char* ws = (char*)d_ws;
  short*  Xn    = (short*)(ws + 0);          //  32 MiB: 8192x2048 bf16
  short*  WinT  = (short*)(ws + 33554432);   //  24 MiB: 6144x2048 bf16
  short*  WoutT = (short*)(ws + 58720256);   //   8 MiB: 2048x2048 bf16
  short*  qkv   = (short*)(ws + 67108864);   //  64 MiB: 8192x4096 bf16 (Q,K only)
  short*  Vt    = (short*)(ws + 134217728);  //  32 MiB: (b,h,128,2048) bf16
  short*  ctx   = (short*)(ws + 167772160);  //  32 MiB: 8192x2048 bf16
  float2* tab   = (float2*)(ws + 201326592); // 512 KiB: 2048x32 cos/sin

  rope_tab_kernel<<<256, 256, 0, stream>>>(tab);
  transpose_cvt<<<dim3(192, 64), dim3(32, 8), 0, stream>>>(Win, WinT, 2048, 6144);
  transpose_cvt<<<dim3(64, 64), dim3(32, 8), 0, stream>>>(Wout, WoutT, 2048, 2048);
  ln_kernel<<<8192, 256, 0, stream>>>(X, lnw, lnb, Xn);
  gemm_bt<0><<<768, 512, 0, stream>>>(Xn, WinT, qkv, Vt, tab, nullptr, nullptr, 8192, 6144, 2048);
  attn_kernel<<<1024, 256, 0, stream>>>(qkv, Vt, ctx);
  gemm_bt<1><<<256, 512, 0, stream>>>(ctx, WoutT, nullptr, nullptr, nullptr, out, X, 8192, 2048, 2048);
}